// Round 1
// baseline (282.775 us; speedup 1.0000x reference)
//
#include <hip/hip_runtime.h>
#include <hip/hip_bf16.h>
#include <stdint.h>

typedef __attribute__((ext_vector_type(4))) float f32x4;
typedef __attribute__((ext_vector_type(8))) short short8;

#define B_   32
#define L_   512
#define DE_  512
#define S_   32
#define ED_  128
#define AD_  256
#define HD_  512
#define VOC_ 32000
#define M_   1024

__device__ __forceinline__ unsigned short f2bf(float f){
  union { float f; unsigned int u; } v; v.f = f;
  unsigned int u = v.u;
  unsigned int r = (u + 0x7FFFu + ((u >> 16) & 1u)) >> 16;  // RNE
  return (unsigned short)r;
}

__device__ __forceinline__ float tanh_fast(float x){
  float t = __expf(2.0f * x);
  return (t - 1.0f) * __builtin_amdgcn_rcpf(t + 1.0f);
}

__device__ __forceinline__ void gl_lds16(const void* g, void* l){
  __builtin_amdgcn_global_load_lds(
      (const __attribute__((address_space(1))) unsigned int*)g,
      (__attribute__((address_space(3))) unsigned int*)l, 16, 0, 0);
}

// ---------------- f32 -> bf16 conversion (vectorized) ----------------
extern "C" __global__ void __launch_bounds__(256)
k_cvt(const float* __restrict__ src, unsigned short* __restrict__ dst, int n4){
  int stride = gridDim.x * 256;
  for (int i = blockIdx.x * 256 + threadIdx.x; i < n4; i += stride){
    f32x4 v = ((const f32x4*)src)[i];
    ushort4 o;
    o.x = f2bf(v[0]); o.y = f2bf(v[1]); o.z = f2bf(v[2]); o.w = f2bf(v[3]);
    ((ushort4*)dst)[i] = o;
  }
}

// ---------------- dec_query [32][256] and hidden [32][512] ----------------
extern "C" __global__ void __launch_bounds__(256)
k_small(const float* __restrict__ pos, const float* __restrict__ dW, const float* __restrict__ db,
        const float* __restrict__ hW, const float* __restrict__ hb,
        float* __restrict__ dq, float* __restrict__ hidden){
  int t = blockIdx.x * 256 + threadIdx.x;
  if (t < S_ * AD_){
    int s = t >> 8, a = t & 255;
    const float* p = pos + s * ED_;
    const float* wrow = dW + a * ED_;
    float acc = db[a];
    #pragma unroll 4
    for (int e = 0; e < ED_; ++e) acc += p[e] * wrow[e];
    dq[t] = acc;
  } else if (t < S_ * AD_ + S_ * HD_){
    int u = t - S_ * AD_;
    int s = u >> 9, h = u & 511;
    const float* p = pos + s * ED_;
    const float* wrow = hW + h * ED_;
    float acc = hb[h];
    #pragma unroll 4
    for (int e = 0; e < ED_; ++e) acc += p[e] * wrow[e];
    hidden[u] = acc;
  }
}

// ---------------- enc_proj GEMM: [16384x512]bf16 @ [256x512]bf16^T -> f32 + bias ----------
extern "C" __global__ void __launch_bounds__(256)
k_gemm_encp(const unsigned short* __restrict__ A, const unsigned short* __restrict__ Bt,
            const float* __restrict__ bias, float* __restrict__ C){
  __shared__ unsigned short As[128 * 32];
  __shared__ unsigned short Bs[128 * 32];
  int bm = blockIdx.x >> 1, bn = blockIdx.x & 1;
  int tid = threadIdx.x, wid = tid >> 6, lane = tid & 63;
  int fr = lane & 15, fq = lane >> 4;
  int wm = wid >> 1, wn = wid & 1;
  f32x4 acc[4][4];
  #pragma unroll
  for (int i = 0; i < 4; ++i)
    #pragma unroll
    for (int j = 0; j < 4; ++j) acc[i][j] = (f32x4)0.0f;

  for (int k0 = 0; k0 < 512; k0 += 32){
    __syncthreads();
    #pragma unroll
    for (int i = 0; i < 2; ++i){
      int seg = wid * 2 + i;
      int row = seg * 16 + (lane >> 2);
      int col = (lane & 3) * 8;
      gl_lds16(A  + (size_t)(bm * 128 + row) * 512 + k0 + col, &As[seg * 512]);
      gl_lds16(Bt + (size_t)(bn * 128 + row) * 512 + k0 + col, &Bs[seg * 512]);
    }
    __syncthreads();
    short8 a[4], b[4];
    #pragma unroll
    for (int mf = 0; mf < 4; ++mf) a[mf] = *(const short8*)&As[(wm * 64 + mf * 16 + fr) * 32 + fq * 8];
    #pragma unroll
    for (int nf = 0; nf < 4; ++nf) b[nf] = *(const short8*)&Bs[(wn * 64 + nf * 16 + fr) * 32 + fq * 8];
    #pragma unroll
    for (int mf = 0; mf < 4; ++mf)
      #pragma unroll
      for (int nf = 0; nf < 4; ++nf)
        acc[mf][nf] = __builtin_amdgcn_mfma_f32_16x16x32_bf16(a[mf], b[nf], acc[mf][nf], 0, 0, 0);
  }
  #pragma unroll
  for (int mf = 0; mf < 4; ++mf){
    int row = bm * 128 + wm * 64 + mf * 16 + fq * 4;
    #pragma unroll
    for (int nf = 0; nf < 4; ++nf){
      int col = bn * 128 + wn * 64 + nf * 16 + fr;
      float bv = bias[col];
      #pragma unroll
      for (int j = 0; j < 4; ++j)
        C[(size_t)(row + j) * 256 + col] = acc[mf][nf][j] + bv;
    }
  }
}

// ---------------- attention scores + softmax -> weights [B][S][L] f32 ----------------
extern "C" __global__ void __launch_bounds__(256)
k_attn(const float* __restrict__ encp, const float* __restrict__ dq,
       const float* __restrict__ vW, float* __restrict__ wgt){
  // XCD-bijective swizzle: 1024 blocks, keep all 32 s-blocks of a given b on one XCD
  int idx = blockIdx.x;
  int wg = (idx & 7) * 128 + (idx >> 3);
  int b = wg >> 5, s = wg & 31;
  int tid = threadIdx.x, wid = tid >> 6, lane = tid & 63;
  __shared__ float sc[512];
  __shared__ float redm[4], reds[4];
  f32x4 dq4 = *(const f32x4*)&dq[s * AD_ + lane * 4];
  f32x4 v4  = *(const f32x4*)&vW[lane * 4];
  for (int li = 0; li < 128; ++li){
    int l = wid * 128 + li;
    f32x4 e4 = *(const f32x4*)&encp[(size_t)(b * 512 + l) * 256 + lane * 4];
    float p = 0.0f;
    #pragma unroll
    for (int j = 0; j < 4; ++j) p += tanh_fast(e4[j] + dq4[j]) * v4[j];
    #pragma unroll
    for (int off = 32; off >= 1; off >>= 1) p += __shfl_xor(p, off);
    if (lane == 0) sc[l] = p;
  }
  __syncthreads();
  float a0 = sc[tid], a1 = sc[tid + 256];
  float m = fmaxf(a0, a1);
  #pragma unroll
  for (int off = 32; off >= 1; off >>= 1) m = fmaxf(m, __shfl_xor(m, off));
  if (lane == 0) redm[wid] = m;
  __syncthreads();
  m = fmaxf(fmaxf(redm[0], redm[1]), fmaxf(redm[2], redm[3]));
  float e0 = __expf(a0 - m), e1 = __expf(a1 - m);
  float sum = e0 + e1;
  #pragma unroll
  for (int off = 32; off >= 1; off >>= 1) sum += __shfl_xor(sum, off);
  if (lane == 0) reds[wid] = sum;
  __syncthreads();
  float tot = reds[0] + reds[1] + reds[2] + reds[3];
  float inv = __builtin_amdgcn_rcpf(tot);
  size_t base = (size_t)(b * 32 + s) * 512;
  wgt[base + tid] = e0 * inv;
  wgt[base + tid + 256] = e1 * inv;
}

// ---------------- context: ctx[b*32+s][d] = sum_l w[b,s,l] * enc[b,l,d] -> bf16 ----------
extern "C" __global__ void __launch_bounds__(256)
k_ctx(const float* __restrict__ enc, const float* __restrict__ wgt, unsigned short* __restrict__ ctx){
  int b = blockIdx.x >> 4, dt = blockIdx.x & 15;
  int tid = threadIdx.x;
  __shared__ float wl[32 * 512];
  #pragma unroll 8
  for (int i = 0; i < 64; ++i)
    wl[i * 256 + tid] = wgt[(size_t)b * 16384 + i * 256 + tid];
  __syncthreads();
  int d = dt * 32 + (tid & 31);
  int grp = tid >> 5;
  float acc0 = 0, acc1 = 0, acc2 = 0, acc3 = 0;
  const float* ebase = enc + (size_t)b * 262144 + d;   // 512*512
  const float* w0 = &wl[(grp * 4 + 0) * 512];
  const float* w1 = &wl[(grp * 4 + 1) * 512];
  const float* w2 = &wl[(grp * 4 + 2) * 512];
  const float* w3 = &wl[(grp * 4 + 3) * 512];
  #pragma unroll 8
  for (int l = 0; l < 512; ++l){
    float e = ebase[(size_t)l * 512];
    acc0 += w0[l] * e; acc1 += w1[l] * e; acc2 += w2[l] * e; acc3 += w3[l] * e;
  }
  size_t obase = (size_t)(b * 32 + grp * 4) * 512 + d;
  ctx[obase]        = f2bf(acc0);
  ctx[obase + 512]  = f2bf(acc1);
  ctx[obase + 1024] = f2bf(acc2);
  ctx[obase + 1536] = f2bf(acc3);
}

// ---------------- logh[s][v] = hidden[s] . fcW[v,0:512] + fcb[v] ----------------
extern "C" __global__ void __launch_bounds__(256)
k_logh(const float* __restrict__ hidden, const float* __restrict__ fcW,
       const float* __restrict__ fcb, float* __restrict__ logh){
  __shared__ unsigned short Hs[32 * 32];
  __shared__ unsigned short Bs[128 * 32];
  int bn = blockIdx.x;
  int tid = threadIdx.x, wid = tid >> 6, lane = tid & 63;
  int fr = lane & 15, fq = lane >> 4;
  f32x4 acc[2][2];
  #pragma unroll
  for (int i = 0; i < 2; ++i)
    #pragma unroll
    for (int j = 0; j < 2; ++j) acc[i][j] = (f32x4)0.0f;

  for (int k0 = 0; k0 < 512; k0 += 32){
    __syncthreads();
    {
      int s = tid >> 3, kp = tid & 7;
      f32x4 h4 = *(const f32x4*)&hidden[s * 512 + k0 + kp * 4];
      ushort4 o;
      o.x = f2bf(h4[0]); o.y = f2bf(h4[1]); o.z = f2bf(h4[2]); o.w = f2bf(h4[3]);
      *(ushort4*)&Hs[s * 32 + kp * 4] = o;
    }
    #pragma unroll
    for (int i = 0; i < 4; ++i){
      int c = i * 256 + tid;
      int row = c >> 3, kp = c & 7;
      f32x4 v = *(const f32x4*)&fcW[(size_t)(bn * 128 + row) * 1024 + k0 + kp * 4];
      ushort4 o;
      o.x = f2bf(v[0]); o.y = f2bf(v[1]); o.z = f2bf(v[2]); o.w = f2bf(v[3]);
      *(ushort4*)&Bs[row * 32 + kp * 4] = o;
    }
    __syncthreads();
    short8 a[2], bb[2];
    #pragma unroll
    for (int mf = 0; mf < 2; ++mf) a[mf] = *(const short8*)&Hs[(mf * 16 + fr) * 32 + fq * 8];
    #pragma unroll
    for (int nf = 0; nf < 2; ++nf) bb[nf] = *(const short8*)&Bs[(wid * 32 + nf * 16 + fr) * 32 + fq * 8];
    #pragma unroll
    for (int mf = 0; mf < 2; ++mf)
      #pragma unroll
      for (int nf = 0; nf < 2; ++nf)
        acc[mf][nf] = __builtin_amdgcn_mfma_f32_16x16x32_bf16(a[mf], bb[nf], acc[mf][nf], 0, 0, 0);
  }
  #pragma unroll
  for (int mf = 0; mf < 2; ++mf)
    #pragma unroll
    for (int nf = 0; nf < 2; ++nf){
      int col = bn * 128 + wid * 32 + nf * 16 + fr;
      float bv = fcb[col];
      #pragma unroll
      for (int j = 0; j < 4; ++j){
        int srow = mf * 16 + fq * 4 + j;
        logh[(size_t)srow * VOC_ + col] = acc[mf][nf][j] + bv;
      }
    }
}

// ---------------- main GEMM: out[m][v] = ctx[m] . fcW[v,512:1024] + logh[m&31][v] ----------
extern "C" __global__ void __launch_bounds__(256)
k_gemm_main(const unsigned short* __restrict__ Abf, const float* __restrict__ fcW,
            const float* __restrict__ logh, float* __restrict__ out){
  __shared__ unsigned short As[128 * 32];
  __shared__ unsigned short Bs[128 * 32];
  // 2000 blocks; bijective XCD swizzle (2000 % 8 == 0); bm inner so 8 blocks share a B-panel
  int idx = blockIdx.x;
  int wg = (idx & 7) * 250 + (idx >> 3);
  int bm = wg & 7, bn = wg >> 3;
  int tid = threadIdx.x, wid = tid >> 6, lane = tid & 63;
  int fr = lane & 15, fq = lane >> 4;
  int wm = wid >> 1, wn = wid & 1;
  f32x4 acc[4][4];
  #pragma unroll
  for (int i = 0; i < 4; ++i)
    #pragma unroll
    for (int j = 0; j < 4; ++j) acc[i][j] = (f32x4)0.0f;

  for (int k0 = 0; k0 < 512; k0 += 32){
    __syncthreads();
    #pragma unroll
    for (int i = 0; i < 2; ++i){
      int seg = wid * 2 + i;
      gl_lds16(Abf + (size_t)(bm * 128 + seg * 16 + (lane >> 2)) * 512 + k0 + (lane & 3) * 8,
               &As[seg * 512]);
    }
    {
      int row = tid >> 1, half = tid & 1;
      const float* src = fcW + (size_t)(bn * 128 + row) * 1024 + 512 + k0 + half * 16;
      f32x4 v0 = *(const f32x4*)(src);
      f32x4 v1 = *(const f32x4*)(src + 4);
      f32x4 v2 = *(const f32x4*)(src + 8);
      f32x4 v3 = *(const f32x4*)(src + 12);
      ushort4 o0, o1, o2, o3;
      o0.x = f2bf(v0[0]); o0.y = f2bf(v0[1]); o0.z = f2bf(v0[2]); o0.w = f2bf(v0[3]);
      o1.x = f2bf(v1[0]); o1.y = f2bf(v1[1]); o1.z = f2bf(v1[2]); o1.w = f2bf(v1[3]);
      o2.x = f2bf(v2[0]); o2.y = f2bf(v2[1]); o2.z = f2bf(v2[2]); o2.w = f2bf(v2[3]);
      o3.x = f2bf(v3[0]); o3.y = f2bf(v3[1]); o3.z = f2bf(v3[2]); o3.w = f2bf(v3[3]);
      unsigned short* dstp = &Bs[row * 32 + half * 16];
      *(ushort4*)(dstp)      = o0;
      *(ushort4*)(dstp + 4)  = o1;
      *(ushort4*)(dstp + 8)  = o2;
      *(ushort4*)(dstp + 12) = o3;
    }
    __syncthreads();
    short8 a[4], b[4];
    #pragma unroll
    for (int mf = 0; mf < 4; ++mf) a[mf] = *(const short8*)&As[(wm * 64 + mf * 16 + fr) * 32 + fq * 8];
    #pragma unroll
    for (int nf = 0; nf < 4; ++nf) b[nf] = *(const short8*)&Bs[(wn * 64 + nf * 16 + fr) * 32 + fq * 8];
    #pragma unroll
    for (int mf = 0; mf < 4; ++mf)
      #pragma unroll
      for (int nf = 0; nf < 4; ++nf)
        acc[mf][nf] = __builtin_amdgcn_mfma_f32_16x16x32_bf16(a[mf], b[nf], acc[mf][nf], 0, 0, 0);
  }
  #pragma unroll
  for (int mf = 0; mf < 4; ++mf){
    int rowb = bm * 128 + wm * 64 + mf * 16 + fq * 4;
    #pragma unroll
    for (int nf = 0; nf < 4; ++nf){
      int col = bn * 128 + wn * 64 + nf * 16 + fr;
      #pragma unroll
      for (int j = 0; j < 4; ++j){
        int r = rowb + j;
        out[(size_t)r * VOC_ + col] = acc[mf][nf][j] + logh[(size_t)(r & 31) * VOC_ + col];
      }
    }
  }
}

extern "C" void kernel_launch(void* const* d_in, const int* in_sizes, int n_in,
                              void* d_out, int out_size, void* d_ws, size_t ws_size,
                              hipStream_t stream){
  const float* enc = (const float*)d_in[0];
  // d_in[1] = target_seq (unused: only its shape matters in the reference)
  const float* pos = (const float*)d_in[2];
  const float* dW  = (const float*)d_in[3];
  const float* db  = (const float*)d_in[4];
  const float* eW  = (const float*)d_in[5];
  const float* eb  = (const float*)d_in[6];
  const float* vW  = (const float*)d_in[7];
  // d_in[8] = attn_score_b: constant shift over l, cancels exactly in softmax
  const float* hW  = (const float*)d_in[9];
  const float* hb  = (const float*)d_in[10];
  const float* fcW = (const float*)d_in[11];
  const float* fcb = (const float*)d_in[12];
  float* out = (float*)d_out;

  char* w = (char*)d_ws;
  unsigned short* enc_bf  = (unsigned short*)(w);               // 16,777,216 B
  float*          encp    = (float*)(w + 16777216);             // 16,777,216 B
  unsigned short* ctx     = (unsigned short*)(w + 33554432);    //  1,048,576 B
  float*          logh    = (float*)(w + 34603008);             //  4,096,000 B
  float*          dq      = (float*)(w + 38699008);             //     32,768 B
  float*          hidden  = (float*)(w + 38731776);             //     65,536 B
  unsigned short* encW_bf = (unsigned short*)(w + 38797312);    //    262,144 B
  float*          wgt     = (float*)(w + 39059456);             //  2,097,152 B  (total ~41.2 MB)

  k_cvt<<<dim3(2048), dim3(256), 0, stream>>>(enc, enc_bf, 8388608 / 4);
  k_cvt<<<dim3(128), dim3(256), 0, stream>>>(eW, encW_bf, 131072 / 4);
  k_small<<<dim3(96), dim3(256), 0, stream>>>(pos, dW, db, hW, hb, dq, hidden);
  k_gemm_encp<<<dim3(256), dim3(256), 0, stream>>>(enc_bf, encW_bf, eb, encp);
  k_attn<<<dim3(1024), dim3(256), 0, stream>>>(encp, dq, vW, wgt);
  k_ctx<<<dim3(512), dim3(256), 0, stream>>>(enc, wgt, ctx);
  k_logh<<<dim3(250), dim3(256), 0, stream>>>(hidden, fcW, fcb, logh);
  k_gemm_main<<<dim3(2000), dim3(256), 0, stream>>>(ctx, fcW, logh, out);
}

// Round 2
// 229.654 us; speedup vs baseline: 1.2313x; 1.2313x over previous
//
#include <hip/hip_runtime.h>
#include <hip/hip_bf16.h>
#include <stdint.h>

typedef __attribute__((ext_vector_type(4))) float f32x4;
typedef __attribute__((ext_vector_type(8))) short short8;

#define B_   32
#define L_   512
#define DE_  512
#define S_   32
#define ED_  128
#define AD_  256
#define HD_  512
#define VOC_ 32000
#define M_   1024

__device__ __forceinline__ unsigned short f2bf(float f){
  union { float f; unsigned int u; } v; v.f = f;
  unsigned int u = v.u;
  unsigned int r = (u + 0x7FFFu + ((u >> 16) & 1u)) >> 16;  // RNE
  return (unsigned short)r;
}

__device__ __forceinline__ float bf2f(unsigned short u){
  union { unsigned int u; float f; } v; v.u = ((unsigned int)u) << 16;
  return v.f;
}

__device__ __forceinline__ float tanh_fast(float x){
  float t = __expf(2.0f * x);
  return (t - 1.0f) * __builtin_amdgcn_rcpf(t + 1.0f);
}

__device__ __forceinline__ void gl_lds16(const void* g, void* l){
  __builtin_amdgcn_global_load_lds(
      (const __attribute__((address_space(1))) unsigned int*)g,
      (__attribute__((address_space(3))) unsigned int*)l, 16, 0, 0);
}

// ---------------- generic f32 -> bf16 (contiguous) ----------------
extern "C" __global__ void __launch_bounds__(256)
k_cvt(const float* __restrict__ src, unsigned short* __restrict__ dst, int n4){
  int stride = gridDim.x * 256;
  for (int i = blockIdx.x * 256 + threadIdx.x; i < n4; i += stride){
    f32x4 v = ((const f32x4*)src)[i];
    ushort4 o;
    o.x = f2bf(v[0]); o.y = f2bf(v[1]); o.z = f2bf(v[2]); o.w = f2bf(v[3]);
    ((ushort4*)dst)[i] = o;
  }
}

// ---------------- fcW[:, 512:1024] f32 -> Wc_bf [32000][512] bf16 ----------------
extern "C" __global__ void __launch_bounds__(256)
k_cvtW(const float* __restrict__ fcW, unsigned short* __restrict__ Wc, int n4){
  int stride = gridDim.x * 256;
  for (int i = blockIdx.x * 256 + threadIdx.x; i < n4; i += stride){
    int row = i >> 7;          // 128 f32x4 per 512-col half-row
    int c4  = i & 127;
    f32x4 v = *(const f32x4*)&fcW[(size_t)row * 1024 + 512 + c4 * 4];
    ushort4 o;
    o.x = f2bf(v[0]); o.y = f2bf(v[1]); o.z = f2bf(v[2]); o.w = f2bf(v[3]);
    *(ushort4*)&Wc[(size_t)row * 512 + c4 * 4] = o;
  }
}

// ---------------- dec_query [32][256] f32 and hidden [32][512] bf16 ----------------
extern "C" __global__ void __launch_bounds__(256)
k_small(const float* __restrict__ pos, const float* __restrict__ dW, const float* __restrict__ db,
        const float* __restrict__ hW, const float* __restrict__ hb,
        float* __restrict__ dq, unsigned short* __restrict__ hbf){
  int t = blockIdx.x * 256 + threadIdx.x;
  if (t < S_ * AD_){
    int s = t >> 8, a = t & 255;
    const float* p = pos + s * ED_;
    const float* wrow = dW + a * ED_;
    float acc = db[a];
    #pragma unroll 4
    for (int e = 0; e < ED_; ++e) acc += p[e] * wrow[e];
    dq[t] = acc;
  } else if (t < S_ * AD_ + S_ * HD_){
    int u = t - S_ * AD_;
    int s = u >> 9, h = u & 511;
    const float* p = pos + s * ED_;
    const float* wrow = hW + h * ED_;
    float acc = hb[h];
    #pragma unroll 4
    for (int e = 0; e < ED_; ++e) acc += p[e] * wrow[e];
    hbf[u] = f2bf(acc);
  }
}

// ---------------- enc_proj GEMM: [16384x512]bf16 @ [256x512]bf16^T -> bf16 + bias ----------
extern "C" __global__ void __launch_bounds__(256)
k_gemm_encp(const unsigned short* __restrict__ A, const unsigned short* __restrict__ Bt,
            const float* __restrict__ bias, unsigned short* __restrict__ C){
  __shared__ unsigned short As[128 * 32];
  __shared__ unsigned short Bs[128 * 32];
  int bm = blockIdx.x >> 1, bn = blockIdx.x & 1;
  int tid = threadIdx.x, wid = tid >> 6, lane = tid & 63;
  int fr = lane & 15, fq = lane >> 4;
  int wm = wid >> 1, wn = wid & 1;
  f32x4 acc[4][4];
  #pragma unroll
  for (int i = 0; i < 4; ++i)
    #pragma unroll
    for (int j = 0; j < 4; ++j) acc[i][j] = (f32x4)0.0f;

  for (int k0 = 0; k0 < 512; k0 += 32){
    __syncthreads();
    #pragma unroll
    for (int i = 0; i < 2; ++i){
      int seg = wid * 2 + i;
      int row = seg * 16 + (lane >> 2);
      int col = (lane & 3) * 8;
      gl_lds16(A  + (size_t)(bm * 128 + row) * 512 + k0 + col, &As[seg * 512]);
      gl_lds16(Bt + (size_t)(bn * 128 + row) * 512 + k0 + col, &Bs[seg * 512]);
    }
    __syncthreads();
    short8 a[4], b[4];
    #pragma unroll
    for (int mf = 0; mf < 4; ++mf) a[mf] = *(const short8*)&As[(wm * 64 + mf * 16 + fr) * 32 + fq * 8];
    #pragma unroll
    for (int nf = 0; nf < 4; ++nf) b[nf] = *(const short8*)&Bs[(wn * 64 + nf * 16 + fr) * 32 + fq * 8];
    #pragma unroll
    for (int mf = 0; mf < 4; ++mf)
      #pragma unroll
      for (int nf = 0; nf < 4; ++nf)
        acc[mf][nf] = __builtin_amdgcn_mfma_f32_16x16x32_bf16(a[mf], b[nf], acc[mf][nf], 0, 0, 0);
  }
  #pragma unroll
  for (int mf = 0; mf < 4; ++mf){
    int row = bm * 128 + wm * 64 + mf * 16 + fq * 4;
    #pragma unroll
    for (int nf = 0; nf < 4; ++nf){
      int col = bn * 128 + wn * 64 + nf * 16 + fr;
      float bv = bias[col];
      #pragma unroll
      for (int j = 0; j < 4; ++j)
        C[(size_t)(row + j) * 256 + col] = f2bf(acc[mf][nf][j] + bv);
    }
  }
}

// ---------------- attention scores + softmax -> weights [B][S][L] f32 ----------------
extern "C" __global__ void __launch_bounds__(256)
k_attn(const unsigned short* __restrict__ encp, const float* __restrict__ dq,
       const float* __restrict__ vW, float* __restrict__ wgt){
  int idx = blockIdx.x;
  int wg = (idx & 7) * 128 + (idx >> 3);   // bijective: 1024 % 8 == 0
  int b = wg >> 5, s = wg & 31;
  int tid = threadIdx.x, wid = tid >> 6, lane = tid & 63;
  int half = lane >> 5, a0 = (lane & 31) * 8;
  __shared__ float sc[512];
  __shared__ float redm[4], reds[4];
  f32x4 dqa = *(const f32x4*)&dq[s * AD_ + a0];
  f32x4 dqb = *(const f32x4*)&dq[s * AD_ + a0 + 4];
  f32x4 va  = *(const f32x4*)&vW[a0];
  f32x4 vb  = *(const f32x4*)&vW[a0 + 4];
  for (int it = 0; it < 64; ++it){
    int l = wid * 128 + it * 2 + half;
    short8 e8 = *(const short8*)&encp[((size_t)(b * 512 + l)) * 256 + a0];
    float p = 0.0f;
    #pragma unroll
    for (int j = 0; j < 4; ++j) p += tanh_fast(bf2f((unsigned short)e8[j]) + dqa[j]) * va[j];
    #pragma unroll
    for (int j = 0; j < 4; ++j) p += tanh_fast(bf2f((unsigned short)e8[4 + j]) + dqb[j]) * vb[j];
    #pragma unroll
    for (int off = 16; off >= 1; off >>= 1) p += __shfl_xor(p, off);
    if ((lane & 31) == 0) sc[l] = p;
  }
  __syncthreads();
  float s0 = sc[tid], s1 = sc[tid + 256];
  float m = fmaxf(s0, s1);
  #pragma unroll
  for (int off = 32; off >= 1; off >>= 1) m = fmaxf(m, __shfl_xor(m, off));
  if (lane == 0) redm[wid] = m;
  __syncthreads();
  m = fmaxf(fmaxf(redm[0], redm[1]), fmaxf(redm[2], redm[3]));
  float e0 = __expf(s0 - m), e1 = __expf(s1 - m);
  float sum = e0 + e1;
  #pragma unroll
  for (int off = 32; off >= 1; off >>= 1) sum += __shfl_xor(sum, off);
  if (lane == 0) reds[wid] = sum;
  __syncthreads();
  float tot = reds[0] + reds[1] + reds[2] + reds[3];
  float inv = __builtin_amdgcn_rcpf(tot);
  size_t base = (size_t)(b * 32 + s) * 512;
  wgt[base + tid] = e0 * inv;
  wgt[base + tid + 256] = e1 * inv;
}

// ---------------- context: ctx[b*32+s][d] = sum_l w[b,s,l] * enc[b,l,d] -> bf16 ----------
extern "C" __global__ void __launch_bounds__(256)
k_ctx(const float* __restrict__ enc, const float* __restrict__ wgt, unsigned short* __restrict__ ctx){
  int b = blockIdx.x >> 4, dt = blockIdx.x & 15;
  int tid = threadIdx.x;
  __shared__ float wl[32 * 512];
  #pragma unroll 8
  for (int i = 0; i < 64; ++i)
    wl[i * 256 + tid] = wgt[(size_t)b * 16384 + i * 256 + tid];
  __syncthreads();
  int d = dt * 32 + (tid & 31);
  int grp = tid >> 5;
  float acc0 = 0, acc1 = 0, acc2 = 0, acc3 = 0;
  const float* ebase = enc + (size_t)b * 262144 + d;   // 512*512
  const float* w0 = &wl[(grp * 4 + 0) * 512];
  const float* w1 = &wl[(grp * 4 + 1) * 512];
  const float* w2 = &wl[(grp * 4 + 2) * 512];
  const float* w3 = &wl[(grp * 4 + 3) * 512];
  #pragma unroll 8
  for (int l = 0; l < 512; ++l){
    float e = ebase[(size_t)l * 512];
    acc0 += w0[l] * e; acc1 += w1[l] * e; acc2 += w2[l] * e; acc3 += w3[l] * e;
  }
  size_t obase = (size_t)(b * 32 + grp * 4) * 512 + d;
  ctx[obase]        = f2bf(acc0);
  ctx[obase + 512]  = f2bf(acc1);
  ctx[obase + 1024] = f2bf(acc2);
  ctx[obase + 1536] = f2bf(acc3);
}

// ---------------- logh[s][v] = hidden[s] . fcW[v,0:512] + fcb[v]  (LDS-free) ----------
extern "C" __global__ void __launch_bounds__(256)
k_logh(const unsigned short* __restrict__ hbf, const float* __restrict__ fcW,
       const float* __restrict__ fcb, float* __restrict__ logh){
  int bn = blockIdx.x;                       // 500 blocks x 64 cols
  int tid = threadIdx.x, wid = tid >> 6, lane = tid & 63;
  int fr = lane & 15, fq = lane >> 4;
  int col = bn * 64 + wid * 16 + fr;
  const float* brow = fcW + (size_t)col * 1024;
  f32x4 acc0 = (f32x4)0.0f, acc1 = (f32x4)0.0f;
  #pragma unroll 4
  for (int k0 = 0; k0 < 512; k0 += 32){
    int ko = k0 + fq * 8;
    f32x4 b0 = *(const f32x4*)(brow + ko);
    f32x4 b1 = *(const f32x4*)(brow + ko + 4);
    short8 bfr;
    bfr[0] = (short)f2bf(b0[0]); bfr[1] = (short)f2bf(b0[1]);
    bfr[2] = (short)f2bf(b0[2]); bfr[3] = (short)f2bf(b0[3]);
    bfr[4] = (short)f2bf(b1[0]); bfr[5] = (short)f2bf(b1[1]);
    bfr[6] = (short)f2bf(b1[2]); bfr[7] = (short)f2bf(b1[3]);
    short8 a0 = *(const short8*)&hbf[(size_t)fr * 512 + ko];
    short8 a1 = *(const short8*)&hbf[(size_t)(16 + fr) * 512 + ko];
    acc0 = __builtin_amdgcn_mfma_f32_16x16x32_bf16(a0, bfr, acc0, 0, 0, 0);
    acc1 = __builtin_amdgcn_mfma_f32_16x16x32_bf16(a1, bfr, acc1, 0, 0, 0);
  }
  float bv = fcb[col];
  #pragma unroll
  for (int j = 0; j < 4; ++j){
    logh[(size_t)(fq * 4 + j) * VOC_ + col]      = acc0[j] + bv;
    logh[(size_t)(16 + fq * 4 + j) * VOC_ + col] = acc1[j] + bv;
  }
}

// ---------------- main GEMM: out[m][v] = ctx[m] . Wc[v] + logh[m&31][v] ----------
extern "C" __global__ void __launch_bounds__(256)
k_gemm_main(const unsigned short* __restrict__ Abf, const unsigned short* __restrict__ Wc,
            const float* __restrict__ logh, float* __restrict__ out){
  __shared__ unsigned short As[128 * 32];
  __shared__ unsigned short Bs[128 * 32];
  // 2000 blocks; bijective XCD swizzle (2000 % 8 == 0); bm inner so 8 blocks share a B-panel
  int idx = blockIdx.x;
  int wg = (idx & 7) * 250 + (idx >> 3);
  int bm = wg & 7, bn = wg >> 3;
  int tid = threadIdx.x, wid = tid >> 6, lane = tid & 63;
  int fr = lane & 15, fq = lane >> 4;
  int wm = wid >> 1, wn = wid & 1;
  f32x4 acc[4][4];
  #pragma unroll
  for (int i = 0; i < 4; ++i)
    #pragma unroll
    for (int j = 0; j < 4; ++j) acc[i][j] = (f32x4)0.0f;

  for (int k0 = 0; k0 < 512; k0 += 32){
    __syncthreads();
    #pragma unroll
    for (int i = 0; i < 2; ++i){
      int seg = wid * 2 + i;
      int row = seg * 16 + (lane >> 2);
      int col = (lane & 3) * 8;
      gl_lds16(Abf + (size_t)(bm * 128 + row) * 512 + k0 + col, &As[seg * 512]);
      gl_lds16(Wc  + (size_t)(bn * 128 + row) * 512 + k0 + col, &Bs[seg * 512]);
    }
    __syncthreads();
    short8 a[4], b[4];
    #pragma unroll
    for (int mf = 0; mf < 4; ++mf) a[mf] = *(const short8*)&As[(wm * 64 + mf * 16 + fr) * 32 + fq * 8];
    #pragma unroll
    for (int nf = 0; nf < 4; ++nf) b[nf] = *(const short8*)&Bs[(wn * 64 + nf * 16 + fr) * 32 + fq * 8];
    #pragma unroll
    for (int mf = 0; mf < 4; ++mf)
      #pragma unroll
      for (int nf = 0; nf < 4; ++nf)
        acc[mf][nf] = __builtin_amdgcn_mfma_f32_16x16x32_bf16(a[mf], b[nf], acc[mf][nf], 0, 0, 0);
  }
  #pragma unroll
  for (int mf = 0; mf < 4; ++mf){
    int rowb = bm * 128 + wm * 64 + mf * 16 + fq * 4;
    #pragma unroll
    for (int nf = 0; nf < 4; ++nf){
      int col = bn * 128 + wn * 64 + nf * 16 + fr;
      #pragma unroll
      for (int j = 0; j < 4; ++j){
        int r = rowb + j;
        out[(size_t)r * VOC_ + col] = acc[mf][nf][j] + logh[(size_t)(r & 31) * VOC_ + col];
      }
    }
  }
}

extern "C" void kernel_launch(void* const* d_in, const int* in_sizes, int n_in,
                              void* d_out, int out_size, void* d_ws, size_t ws_size,
                              hipStream_t stream){
  const float* enc = (const float*)d_in[0];
  // d_in[1] = target_seq (unused: only its shape matters in the reference)
  const float* pos = (const float*)d_in[2];
  const float* dW  = (const float*)d_in[3];
  const float* db  = (const float*)d_in[4];
  const float* eW  = (const float*)d_in[5];
  const float* eb  = (const float*)d_in[6];
  const float* vW  = (const float*)d_in[7];
  // d_in[8] = attn_score_b: constant over l, cancels exactly in softmax
  const float* hW  = (const float*)d_in[9];
  const float* hb  = (const float*)d_in[10];
  const float* fcW = (const float*)d_in[11];
  const float* fcb = (const float*)d_in[12];
  float* out = (float*)d_out;

  char* w = (char*)d_ws;
  unsigned short* Wc_bf   = (unsigned short*)(w);               // 32,768,000 B
  unsigned short* enc_bf  = (unsigned short*)(w + 32768000);    // 16,777,216 B
  unsigned short* encp_bf = (unsigned short*)(w + 49545216);    //  8,388,608 B
  unsigned short* ctx     = (unsigned short*)(w + 57933824);    //  1,048,576 B
  float*          logh    = (float*)(w + 58982400);             //  4,096,000 B
  float*          dq      = (float*)(w + 63078400);             //     32,768 B
  unsigned short* hbf     = (unsigned short*)(w + 63111168);    //     32,768 B
  unsigned short* encW_bf = (unsigned short*)(w + 63143936);    //    262,144 B
  float*          wgt     = (float*)(w + 63406080);             //  2,097,152 B (total ~65.5 MB)

  k_cvt<<<dim3(2048), dim3(256), 0, stream>>>(enc, enc_bf, 8388608 / 4);
  k_cvt<<<dim3(128), dim3(256), 0, stream>>>(eW, encW_bf, 131072 / 4);
  k_cvtW<<<dim3(2048), dim3(256), 0, stream>>>(fcW, Wc_bf, 32000 * 512 / 4);
  k_small<<<dim3(96), dim3(256), 0, stream>>>(pos, dW, db, hW, hb, dq, hbf);
  k_gemm_encp<<<dim3(256), dim3(256), 0, stream>>>(enc_bf, encW_bf, eb, encp_bf);
  k_attn<<<dim3(1024), dim3(256), 0, stream>>>(encp_bf, dq, vW, wgt);
  k_ctx<<<dim3(512), dim3(256), 0, stream>>>(enc, wgt, ctx);
  k_logh<<<dim3(500), dim3(256), 0, stream>>>(hbf, fcW, fcb, logh);
  k_gemm_main<<<dim3(2000), dim3(256), 0, stream>>>(ctx, Wc_bf, logh, out);
}